// Round 12
// baseline (212.931 us; speedup 1.0000x reference)
//
#include <hip/hip_runtime.h>

// Multires hash-grid encode (2D, instant-NGP style). Round 15 (= round 14
// resubmitted verbatim: bench died to infra "container failed twice" before
// compiling/running anything).
//
// Theory: during a hashed window each XCD L2 (4.0 MiB) must hold the
// 4.19-MiB table PLUS ~4 MiB ws store-allocations PLUS ~4 MiB streaming x
// reads. ws/x have zero reuse but evict hot table lines -> the ~110 MiB of
// FETCH above compulsory and the ~8 us we sit above the request-rate floor
// two rounds running. Fix: non-temporal ws stores + x loads (early-evict,
// keep L2 for the table). R3 tested nt bundled with a 2pt/thread
// restructure and we blamed nt for the regression; R5's MLP-null result
// says the restructure was at fault. Clean isolation this round.
//
// Everything else identical to R13 (197.5 us): full pairing, XCD-affine
// hashed levels, time-separated 14/15, merged dense, 64-pt pass-2 tiles.

static constexpr int  kPoints    = 524288;
static constexpr int  kLevels    = 16;
static constexpr int  kStartHash = 6;
static constexpr unsigned kPs1     = 19349663u;
static constexpr unsigned kEntries = 524309u;
static constexpr unsigned kR32     = 352277u;   // 2^32 mod kEntries

typedef float v2f __attribute__((ext_vector_type(2)));
typedef float v4f __attribute__((ext_vector_type(4)));

__device__ __forceinline__ void nt_store2(float2* p, const float2 v) {
    v2f t; t.x = v.x; t.y = v.y;
    __builtin_nontemporal_store(t, (v2f*)p);
}
__device__ __forceinline__ float2 nt_load2(const float2* p) {
    const v2f t = __builtin_nontemporal_load((const v2f*)p);
    return make_float2(t.x, t.y);
}
__device__ __forceinline__ void nt_store4(float4* p, const float4 v) {
    v4f t; t.x = v.x; t.y = v.y; t.z = v.z; t.w = v.w;
    __builtin_nontemporal_store(t, (v4f*)p);
}

__constant__ unsigned c_level_off[kLevels] = {
    0u, 289u, 1378u, 5603u, 22244u, 88293u, 351462u,
    875771u, 1400080u, 1924389u, 2448698u, 2973007u,
    3497316u, 4021625u, 4545934u, 5070243u
};

struct Corners {
    float    w00, w01, w10, w11;
    unsigned i00, i01, i10, i11;   // absolute table indices (level base folded in)
};

__device__ __forceinline__ Corners prep_level(const float2 p, const int l)
{
    const int   scale_i = 16 << l;
    const float scale_f = (float)scale_i;

    const float fx = p.x * scale_f;
    const float fy = p.y * scale_f;

    // coords in [0,1) -> indices nonnegative, max ~524289 at level 15: u32 ok.
    const unsigned ix0 = (unsigned)(int)fx;
    const unsigned iy0 = (unsigned)(int)fy;
    const unsigned ix1 = (unsigned)(int)(fx + 1.0f);   // NOT always ix0+1 (fp rounding)
    const unsigned iy1 = (unsigned)(int)(fy + 1.0f);

    const float ox = fx - (float)ix0;
    const float oy = fy - (float)iy0;

    const float wx1 = fminf(fmaxf(ox, 0.0f), 1.0f);
    const float wx0 = fminf(fmaxf(1.0f - ox, 0.0f), 1.0f);
    const float wy1 = fminf(fmaxf(oy, 0.0f), 1.0f);
    const float wy0 = fminf(fmaxf(1.0f - oy, 0.0f), 1.0f);

    unsigned i00, i01, i10, i11;
    if (l < kStartHash) {
        const unsigned stride = (unsigned)(scale_i + 1);
        i00 = ix0 * stride + iy0;
        i01 = ix0 * stride + iy1;
        i10 = ix1 * stride + iy0;
        i11 = ix1 * stride + iy1;
    } else {
        // 32-bit replication of ((ix ^ (iy*PS1)) % E), bit-exact vs int64:
        // hy = iy*PS1 = hi*2^32+lo, hi <= 2362, ix < 2^20 so xor touches lo only.
        // (hi*2^32 + (lo^ix)) % E = ((hi*R32)%E + (lo^ix)%E) cond-sub E.
        const unsigned long long hy0 = (unsigned long long)iy0 * kPs1;
        const unsigned long long hy1 = (unsigned long long)iy1 * kPs1;
        const unsigned lo0 = (unsigned)hy0, hi0 = (unsigned)(hy0 >> 32);
        const unsigned lo1 = (unsigned)hy1, hi1 = (unsigned)(hy1 >> 32);
        const unsigned a0 = (hi0 * kR32) % kEntries;   // hi*R32 < 2^30
        const unsigned a1 = (hi1 * kR32) % kEntries;
        i00 = a0 + ((lo0 ^ ix0) % kEntries); if (i00 >= kEntries) i00 -= kEntries;
        i01 = a1 + ((lo1 ^ ix0) % kEntries); if (i01 >= kEntries) i01 -= kEntries;
        i10 = a0 + ((lo0 ^ ix1) % kEntries); if (i10 >= kEntries) i10 -= kEntries;
        i11 = a1 + ((lo1 ^ ix1) % kEntries); if (i11 >= kEntries) i11 -= kEntries;
    }

    Corners c;
    const unsigned base = c_level_off[l];
    c.i00 = base + i00; c.i01 = base + i01;
    c.i10 = base + i10; c.i11 = base + i11;
    c.w00 = wx0 * wy0;  c.w01 = wx0 * wy1;
    c.w10 = wx1 * wy0;  c.w11 = wx1 * wy1;
    return c;
}

// Load tbl[ia], tbl[ib]. If adjacent (either order), one 16-B load at the
// lower index serves both (8-B alignment is legal for dwordx4 on gfx950;
// both covered entries are valid, so never OOB). Tested on exact indices.
__device__ __forceinline__ void load_pair(
    const float2* __restrict__ tbl, const unsigned ia, const unsigned ib,
    float2& va, float2& vb)
{
    if (ib == ia + 1u) {
        v4f q; __builtin_memcpy(&q, &tbl[ia], 16);
        va = make_float2(q.x, q.y);
        vb = make_float2(q.z, q.w);
    } else if (ia == ib + 1u) {
        v4f q; __builtin_memcpy(&q, &tbl[ib], 16);
        vb = make_float2(q.x, q.y);
        va = make_float2(q.z, q.w);
    } else {
        va = tbl[ia];
        vb = tbl[ib];
    }
}

__device__ __forceinline__ float2 gather_level(
    const float2* __restrict__ tbl, const Corners& c, const bool hashed)
{
    float2 v00, v01, v10, v11;
    if (!hashed) {
        // dense: y-neighbors adjacent ALWAYS (i01 == i00+1) -> 100% pairing
        load_pair(tbl, c.i00, c.i01, v00, v01);
        load_pair(tbl, c.i10, c.i11, v10, v11);
    } else {
        // hashed: ix0 even -> xor flips bit 0 -> i10 = i00 +/- 1 (~50%)
        load_pair(tbl, c.i00, c.i10, v00, v10);
        load_pair(tbl, c.i01, c.i11, v01, v11);
    }
    return make_float2(
        c.w00 * v00.x + c.w01 * v01.x + c.w10 * v10.x + c.w11 * v11.x,
        c.w00 * v00.y + c.w01 * v01.y + c.w10 * v10.y + c.w11 * v11.y);
}

// ---- Pass 1: XCD-affine hashed + time-separated 14/15 + merged dense ----
// Grid: 2816 slots x 8 XCDs = 22528 blocks. Disjoint slot ranges = disjoint
// time windows; live table per XCD-L2 <= 4.19 MiB at all times.
// NEW: ws stores and x loads are NON-TEMPORAL (zero-reuse streams must not
// evict the hot table from L2).
__global__ __launch_bounds__(256) void level_pass(
    const float2* __restrict__ x,
    const float2* __restrict__ tbl,
    float2* __restrict__ ws)
{
    const int b    = blockIdx.x;
    const int xcd  = b & 7;         // blockIdx%8 round-robins the 8 XCDs
    const int slot = b >> 3;        // 0..2815

    if (slot < 2048) {
        const int level = 6 + xcd;  // one hashed table per XCD -> L2 hits
        const int pblk  = slot;
        const int n = (pblk << 8) | threadIdx.x;
        const float2 p = nt_load2(&x[n]);
        const float2 r = gather_level(tbl, prep_level(p, level), true);
        nt_store2(&ws[((size_t)pblk << 12) + (level << 8) + threadIdx.x], r);
    } else if (slot < 2304) {
        const int pblk = xcd * 256 + (slot - 2048);   // level 14, 0..2047
        const int n = (pblk << 8) | threadIdx.x;
        const float2 p = nt_load2(&x[n]);
        const float2 r = gather_level(tbl, prep_level(p, 14), true);
        nt_store2(&ws[((size_t)pblk << 12) + (14 << 8) + threadIdx.x], r);
    } else if (slot < 2560) {
        const int pblk = xcd * 256 + (slot - 2304);   // level 15, 0..2047
        const int n = (pblk << 8) | threadIdx.x;
        const float2 p = nt_load2(&x[n]);
        const float2 r = gather_level(tbl, prep_level(p, 15), true);
        nt_store2(&ws[((size_t)pblk << 12) + (15 << 8) + threadIdx.x], r);
    } else {
        const int pblk = xcd * 256 + (slot - 2560);   // dense, 0..2047
        const int n = (pblk << 8) | threadIdx.x;
        const float2 p = nt_load2(&x[n]);             // x once for 6 levels
        float2* wb = ws + ((size_t)pblk << 12) + threadIdx.x;
#pragma unroll
        for (int level = 0; level < kStartHash; ++level) {
            const float2 r = gather_level(tbl, prep_level(p, level), false);
            nt_store2(wb + (level << 8), r);
        }
    }
}

// ---- Pass 2: 64-point LDS tiles, grid 8192 (at its 128-MiB BW floor) ----
static constexpr int kT2S = 66;     // stride: 4*66 mod 32 = 8 -> <=2-way (free)

__global__ __launch_bounds__(256) void transpose_out(
    const float2* __restrict__ ws,
    float4* __restrict__ out)
{
    __shared__ float2 lds[kLevels][kT2S];   // 8.4 KB

    const int t = threadIdx.x;
    const int b = blockIdx.x;               // 8192 tiles of 64 points
    const int chunk = b >> 2;               // 256-pt ws chunk
    const int coff  = (b & 3) << 6;         // 64-pt offset inside chunk
    const float2* __restrict__ base = ws + ((size_t)chunk << 12) + coff;

#pragma unroll
    for (int k = 0; k < 4; ++k) {
        const int e = (k << 8) + t;         // 0..1023 = 16 levels x 64 pts
        const int l = e >> 6;
        const int cc = e & 63;
        lds[l][cc] = nt_load2(&base[(l << 8) + cc]);  // coalesced 512-B runs
    }

    __syncthreads();

    float4* o = out + ((size_t)b << 9);     // 64 pts * 8 float4
#pragma unroll
    for (int k = 0; k < 2; ++k) {
        const int g  = (k << 8) + t;        // 0..511
        const int nl = g >> 3;              // local point
        const int i  = g & 7;               // float4 index in the 32-float row
        const float2 a  = lds[2 * i][nl];
        const float2 bb = lds[2 * i + 1][nl];
        nt_store4(&o[g], make_float4(a.x, a.y, bb.x, bb.y));
    }
}

// ---- Fallback: single-pass (if ws too small) ----------------------------
__global__ __launch_bounds__(256) void hashgrid_fwd(
    const float2* __restrict__ x,
    const float2* __restrict__ tbl,
    float4* __restrict__ out)
{
    const int n = blockIdx.x * blockDim.x + threadIdx.x;
    if (n >= kPoints) return;
    const float2 p = x[n];
    float acc[2 * kLevels];
#pragma unroll
    for (int l = 0; l < kLevels; ++l) {
        const float2 r = gather_level(tbl, prep_level(p, l), l >= kStartHash);
        acc[2 * l + 0] = r.x;
        acc[2 * l + 1] = r.y;
    }
    float4* o = out + (size_t)n * 8;
#pragma unroll
    for (int i = 0; i < 8; ++i)
        o[i] = make_float4(acc[4 * i + 0], acc[4 * i + 1],
                           acc[4 * i + 2], acc[4 * i + 3]);
}

extern "C" void kernel_launch(void* const* d_in, const int* in_sizes, int n_in,
                              void* d_out, int out_size, void* d_ws, size_t ws_size,
                              hipStream_t stream) {
    const float2* x   = (const float2*)d_in[0];
    const float2* tbl = (const float2*)d_in[1];

    const size_t ws_needed = (size_t)kLevels * kPoints * sizeof(float2); // 64 MiB
    if (ws_size >= ws_needed) {
        float2* ws = (float2*)d_ws;
        level_pass<<<2816 * 8, 256, 0, stream>>>(x, tbl, ws);
        transpose_out<<<kPoints / 64, 256, 0, stream>>>(ws, (float4*)d_out);
    } else {
        hashgrid_fwd<<<kPoints / 256, 256, 0, stream>>>(x, tbl, (float4*)d_out);
    }
}